// Round 5
// baseline (730.787 us; speedup 1.0000x reference)
//
#include <hip/hip_runtime.h>
#include <hip/hip_bf16.h>

#define F_IN   1024
#define H_DIM  128
#define D_VQE  64
#define K_CODES 512

typedef __attribute__((ext_vector_type(8))) short s8v;   // 8 bf16 = one MFMA A/B frag
typedef __attribute__((ext_vector_type(4))) float f4v;   // MFMA C/D frag

static __device__ __forceinline__ unsigned f2bf(float f) {
    unsigned u = __builtin_bit_cast(unsigned, f);
    return (u + 0x7fffu + ((u >> 16) & 1u)) >> 16;   // RNE, no NaN inputs here
}

static __device__ __forceinline__ f4v mfma16x16x32(s8v a, s8v b, f4v c) {
    return __builtin_amdgcn_mfma_f32_16x16x32_bf16(a, b, c, 0, 0, 0);
}

// ---------------- weight prep: 7 tower weights fp32 [K,N] -> bf16 W^T [N][K] ----------------
__global__ __launch_bounds__(256) void conv_weights(
    const float* __restrict__ W0,  // [1024,128]
    const float* __restrict__ W1, const float* __restrict__ W2,
    const float* __restrict__ W3, const float* __restrict__ W4,
    const float* __restrict__ W5, const float* __restrict__ W6,  // each [128,128]
    short* __restrict__ out)
{
    int g = blockIdx.x * 256 + threadIdx.x;
    if (g < 131072) {
        int n = g >> 10, k = g & 1023;
        out[g] = (short)f2bf(W0[k * 128 + n]);
    } else {
        int r = g - 131072;
        int which = r >> 14, o = r & 16383;
        int n = o >> 7, k = o & 127;
        const float* Ws[6] = {W1, W2, W3, W4, W5, W6};
        out[131072 + which * 16384 + n * 128 + k] = (short)f2bf(Ws[which][k * 128 + n]);
    }
}

// ---------------- e0: [B,1024] fp32 -> relu(x@W_e0+b) -> bf16 [B,128], MFMA (verified) ----------------
__global__ __launch_bounds__(256) void gemm_e0(
    const float* __restrict__ A,     // [B,1024] fp32
    const short* __restrict__ Wt,    // [128][1024] bf16 (n-major)
    const float* __restrict__ bias,  // [128] fp32
    short* __restrict__ out)         // [B,128] bf16
{
    __shared__ __align__(16) char smem[36864];
    short* As = (short*)smem;            // [128][72] bf16 chunk (k width 64)
    short* Bs = (short*)(smem + 18432);  // [128][72] bf16 chunk
    short* Cs = (short*)smem;            // [128][136] epilogue staging (overlaps)

    const int t = threadIdx.x;
    const int lane = t & 63, w = t >> 6;
    const int l15 = lane & 15, q = lane >> 4;
    const size_t row0 = (size_t)blockIdx.x * 128;

    f4v acc[2][8];
#pragma unroll
    for (int i = 0; i < 2; ++i)
#pragma unroll
        for (int j = 0; j < 8; ++j) acc[i][j] = {0.f, 0.f, 0.f, 0.f};

    for (int ch = 0; ch < 16; ++ch) {   // k0 = ch*64
        __syncthreads();
#pragma unroll
        for (int i = 0; i < 8; ++i) {
            int c = t + 256 * i;
            int r = c >> 4, c4 = c & 15;
            float4 a4 = *(const float4*)(A + (row0 + r) * 1024 + ch * 64 + c4 * 4);
            unsigned p01 = f2bf(a4.x) | (f2bf(a4.y) << 16);
            unsigned p23 = f2bf(a4.z) | (f2bf(a4.w) << 16);
            *(int2*)(As + r * 72 + c4 * 4) = make_int2((int)p01, (int)p23);
        }
#pragma unroll
        for (int i = 0; i < 4; ++i) {
            int c = t + 256 * i;
            int n = c >> 3, c16 = c & 7;
            *(int4*)(Bs + n * 72 + c16 * 8) = *(const int4*)(Wt + (size_t)n * 1024 + ch * 64 + c16 * 8);
        }
        __syncthreads();
#pragma unroll
        for (int kc = 0; kc < 2; ++kc) {
            int kb = kc * 32 + q * 8;
            s8v a0 = *(const s8v*)(As + (w * 32 + l15) * 72 + kb);
            s8v a1 = *(const s8v*)(As + (w * 32 + 16 + l15) * 72 + kb);
#pragma unroll
            for (int ct = 0; ct < 8; ++ct) {
                s8v b = *(const s8v*)(Bs + (ct * 16 + l15) * 72 + kb);
                acc[0][ct] = mfma16x16x32(a0, b, acc[0][ct]);
                acc[1][ct] = mfma16x16x32(a1, b, acc[1][ct]);
            }
        }
    }

    float bias_v[8];
#pragma unroll
    for (int ct = 0; ct < 8; ++ct) bias_v[ct] = bias[ct * 16 + l15];

    __syncthreads();
#pragma unroll
    for (int rt = 0; rt < 2; ++rt)
#pragma unroll
        for (int ct = 0; ct < 8; ++ct)
#pragma unroll
            for (int reg = 0; reg < 4; ++reg) {
                float v = acc[rt][ct][reg] + bias_v[ct];
                v = fmaxf(v, 0.f);
                Cs[(w * 32 + rt * 16 + q * 4 + reg) * 136 + ct * 16 + l15] = (short)f2bf(v);
            }
    __syncthreads();
#pragma unroll
    for (int i = 0; i < 8; ++i) {
        int c = t + 256 * i;
        int r = c >> 4, c16 = c & 15;
        *(int4*)(out + (row0 + r) * 128 + c16 * 8) = *(const int4*)(Cs + r * 136 + c16 * 8);
    }
}

// ---------------- fused tower tail: one kernel = e1,e2,a0,a1+softmax,c0,c1+critic ----------------
// Per-stage math is lifted verbatim from the verified gemm_h (identical MFMA accumulation
// order, identical epilogues) -> bitwise-identical outputs. Activations ping-pong between
// two LDS panels; weights restage into a third panel each stage (2 barriers/stage).
// Each wave's A-frags come only from its own 32-row band, so no extra barriers are needed.
// (Round-2 HW evidence: probs/crit bit-stable across all graph replays.)
template<int MODE>
static __device__ __forceinline__ void tail_stage(
    const short* __restrict__ ActX,  // input activations [128][136] bf16 (LDS)
    short* __restrict__ ActY,        // output activations (MODE 0)
    short* __restrict__ Bs,          // weight staging [128][136] bf16 (LDS)
    const short* __restrict__ Wt,    // [128][128] bf16 (n-major, global)
    const float* __restrict__ bias,  // [128] fp32
    const float* __restrict__ w2,    // [128] fp32 (MODE 2)
    const float* __restrict__ b2,    // [1]   fp32 (MODE 2)
    float* __restrict__ out,         // probs (MODE 1) / crit (MODE 2)
    size_t row0, int t, int w, int l15, int q)
{
    __syncthreads();                 // prior stage done reading Bs; ActX writes visible
#pragma unroll
    for (int i = 0; i < 8; ++i) {
        int c = t + 256 * i;
        int n = c >> 4, c16 = c & 15;
        *(int4*)(Bs + n * 136 + c16 * 8) = *(const int4*)(Wt + n * 128 + c16 * 8);
    }
    __syncthreads();

    f4v acc[2][8];
#pragma unroll
    for (int i = 0; i < 2; ++i)
#pragma unroll
        for (int j = 0; j < 8; ++j) acc[i][j] = {0.f, 0.f, 0.f, 0.f};

#pragma unroll
    for (int half = 0; half < 2; ++half)
#pragma unroll
        for (int kc = 0; kc < 2; ++kc) {
            int kg = half * 64 + kc * 32 + q * 8;
            s8v a0 = *(const s8v*)(ActX + (w * 32 + l15) * 136 + kg);
            s8v a1 = *(const s8v*)(ActX + (w * 32 + 16 + l15) * 136 + kg);
#pragma unroll
            for (int ct = 0; ct < 8; ++ct) {
                s8v b = *(const s8v*)(Bs + (ct * 16 + l15) * 136 + kg);
                acc[0][ct] = mfma16x16x32(a0, b, acc[0][ct]);
                acc[1][ct] = mfma16x16x32(a1, b, acc[1][ct]);
            }
        }

    float bias_v[8];
#pragma unroll
    for (int ct = 0; ct < 8; ++ct) bias_v[ct] = bias[ct * 16 + l15];

    if (MODE == 0) {
        // relu -> bf16, into the other LDS activation panel (no global round-trip)
#pragma unroll
        for (int rt = 0; rt < 2; ++rt)
#pragma unroll
            for (int ct = 0; ct < 8; ++ct)
#pragma unroll
                for (int reg = 0; reg < 4; ++reg) {
                    float v = acc[rt][ct][reg] + bias_v[ct];
                    v = fmaxf(v, 0.f);
                    ActY[(w * 32 + rt * 16 + q * 4 + reg) * 136 + ct * 16 + l15] = (short)f2bf(v);
                }
    } else if (MODE == 1) {
        // softmax -> fp32 probs
#pragma unroll
        for (int rt = 0; rt < 2; ++rt)
#pragma unroll
            for (int reg = 0; reg < 4; ++reg) {
                size_t m = row0 + w * 32 + rt * 16 + q * 4 + reg;
                float v[8];
                float mx = -3.4e38f;
#pragma unroll
                for (int ct = 0; ct < 8; ++ct) { v[ct] = acc[rt][ct][reg] + bias_v[ct]; mx = fmaxf(mx, v[ct]); }
#pragma unroll
                for (int off = 1; off < 16; off <<= 1) mx = fmaxf(mx, __shfl_xor(mx, off, 64));
                float s = 0.f;
#pragma unroll
                for (int ct = 0; ct < 8; ++ct) { v[ct] = __expf(v[ct] - mx); s += v[ct]; }
#pragma unroll
                for (int off = 1; off < 16; off <<= 1) s += __shfl_xor(s, off, 64);
                float inv = 1.0f / s;
#pragma unroll
                for (int ct = 0; ct < 8; ++ct) out[m * 128 + ct * 16 + l15] = v[ct] * inv;
            }
    } else {
        // relu + dot(w2) + b2 -> fp32 critic
        float w2v[8];
#pragma unroll
        for (int ct = 0; ct < 8; ++ct) w2v[ct] = w2[ct * 16 + l15];
        float b2s = b2[0];
#pragma unroll
        for (int rt = 0; rt < 2; ++rt)
#pragma unroll
            for (int reg = 0; reg < 4; ++reg) {
                size_t m = row0 + w * 32 + rt * 16 + q * 4 + reg;
                float p = 0.f;
#pragma unroll
                for (int ct = 0; ct < 8; ++ct) p += fmaxf(acc[rt][ct][reg] + bias_v[ct], 0.f) * w2v[ct];
#pragma unroll
                for (int off = 1; off < 16; off <<= 1) p += __shfl_xor(p, off, 64);
                if (l15 == 0) out[m] = p + b2s;
            }
    }
}

__global__ __launch_bounds__(256) void tower_tail(
    const short* __restrict__ A,      // e0 output [B,128] bf16
    const short* __restrict__ Wt_e1, const float* __restrict__ b_e1,
    const short* __restrict__ Wt_e2, const float* __restrict__ b_e2,
    const short* __restrict__ Wt_a0, const float* __restrict__ b_a0,
    const short* __restrict__ Wt_a1, const float* __restrict__ b_a1,
    const short* __restrict__ Wt_c0, const float* __restrict__ b_c0,
    const short* __restrict__ Wt_c1, const float* __restrict__ b_c1,
    const float* __restrict__ W_c2,  const float* __restrict__ b_c2,
    float* __restrict__ probs, float* __restrict__ crit)
{
    __shared__ __align__(16) char smem[104448];
    short* ActA = (short*)smem;            // [128][136] bf16
    short* ActB = (short*)(smem + 34816);  // [128][136] bf16
    short* Bs   = (short*)(smem + 69632);  // [128][136] bf16 weight panel

    const int t = threadIdx.x;
    const int lane = t & 63, w = t >> 6;
    const int l15 = lane & 15, q = lane >> 4;
    const size_t row0 = (size_t)blockIdx.x * 128;

    // stage e0 output into ActA (covered by tail_stage's leading barrier)
#pragma unroll
    for (int i = 0; i < 8; ++i) {
        int c = t + 256 * i;
        int r = c >> 4, c16 = c & 15;
        *(int4*)(ActA + r * 136 + c16 * 8) = *(const int4*)(A + (row0 + r) * 128 + c16 * 8);
    }

    // e1: ActA -> ActB ; e2: ActB -> ActA (emb stays parked in ActA)
    tail_stage<0>(ActA, ActB, Bs, Wt_e1, b_e1, nullptr, nullptr, nullptr, row0, t, w, l15, q);
    tail_stage<0>(ActB, ActA, Bs, Wt_e2, b_e2, nullptr, nullptr, nullptr, row0, t, w, l15, q);
    // actor branch: a0: ActA -> ActB ; a1+softmax: ActB -> probs
    tail_stage<0>(ActA, ActB, Bs, Wt_a0, b_a0, nullptr, nullptr, nullptr, row0, t, w, l15, q);
    tail_stage<1>(ActB, nullptr, Bs, Wt_a1, b_a1, nullptr, nullptr, probs, row0, t, w, l15, q);
    // critic branch: c0: ActA(emb) -> ActB ; c1+dot(W_c2)+b_c2: ActB -> crit
    tail_stage<0>(ActA, ActB, Bs, Wt_c0, b_c0, nullptr, nullptr, nullptr, row0, t, w, l15, q);
    tail_stage<2>(ActB, nullptr, Bs, Wt_c1, b_c1, W_c2, b_c2, crit, row0, t, w, l15, q);
}

// ---------------- xq projection: fp32, verified (bitwise chains) ----------------
// 1 row/lane, 16 cols/thread (wave w -> col quarter w). Per-output single fma chain, k ascending.
__global__ __launch_bounds__(256) void proj64(
    const float* __restrict__ A,     // x [B,1024]
    const float* __restrict__ W,     // W_p [1024,64]
    const float* __restrict__ bias,  // [64]
    float* __restrict__ C)           // xq [B,64]
{
    const int t = threadIdx.x;
    const int lane = t & 63;
    const int c0 = __builtin_amdgcn_readfirstlane((t >> 6) << 4);  // wave-uniform col base
    const size_t row = (size_t)blockIdx.x * 64 + lane;
    const float* xr = A + row * 1024;

    float acc[16];
#pragma unroll
    for (int c = 0; c < 16; ++c) acc[c] = 0.f;

    for (int k4 = 0; k4 < 1024; k4 += 4) {
        float4 xv = *(const float4*)(xr + k4);
        float xs[4] = {xv.x, xv.y, xv.z, xv.w};
#pragma unroll
        for (int kk = 0; kk < 4; ++kk) {
            const float* wrow = W + (size_t)(k4 + kk) * 64 + c0;   // uniform -> s_load
#pragma unroll
            for (int c = 0; c < 16; ++c)
                acc[c] = __builtin_fmaf(xs[kk], wrow[c], acc[c]);
        }
    }
#pragma unroll
    for (int c = 0; c < 16; c += 4) {
        float4 o = {acc[c] + bias[c0 + c], acc[c + 1] + bias[c0 + c + 1],
                    acc[c + 2] + bias[c0 + c + 2], acc[c + 3] + bias[c0 + c + 3]};
        *(float4*)(C + row * 64 + c0 + c) = o;
    }
}

// ---------------- VQ part 1: E in VGPRs (2 codes/thread), xq via scalar loads (verified) ----------------
__global__ __launch_bounds__(256) void vq_part(
    const float* __restrict__ xq, const float* __restrict__ E,
    unsigned long long* __restrict__ part)    // [B][4] per-wave best keys
{
    __shared__ float sxs[64];
    const int t = threadIdx.x;
    const int lane = t & 63, w = t >> 6;
    const size_t row0 = (size_t)blockIdx.x * 64;
    const int j0 = 2 * t, j1 = 2 * t + 1;

    // load this thread's two codebook rows into registers
    float e0r[64], e1r[64];
#pragma unroll
    for (int d = 0; d < 64; d += 4) {
        float4 v = *(const float4*)(E + (size_t)j0 * 64 + d);
        e0r[d] = v.x; e0r[d + 1] = v.y; e0r[d + 2] = v.z; e0r[d + 3] = v.w;
        float4 u = *(const float4*)(E + (size_t)j1 * 64 + d);
        e1r[d] = u.x; e1r[d + 1] = u.y; e1r[d + 2] = u.z; e1r[d + 3] = u.w;
    }
    float en0 = 0.f, en1 = 0.f;
#pragma unroll
    for (int d = 0; d < 64; ++d) {
        en0 = __builtin_fmaf(e0r[d], e0r[d], en0);
        en1 = __builtin_fmaf(e1r[d], e1r[d], en1);
    }

    // sx for the block's 64 rows (wave 0), single ascending chain per row
    if (w == 0) {
        const float* xr = xq + (row0 + lane) * 64;
        float sx = 0.f;
#pragma unroll
        for (int d = 0; d < 64; d += 4) {
            float4 v = *(const float4*)(xr + d);
            sx = __builtin_fmaf(v.x, v.x, sx);
            sx = __builtin_fmaf(v.y, v.y, sx);
            sx = __builtin_fmaf(v.z, v.z, sx);
            sx = __builtin_fmaf(v.w, v.w, sx);
        }
        sxs[lane] = sx;
    }
    __syncthreads();

    for (int rr = 0; rr < 64; rr += 2) {
        const float* x0 = xq + (row0 + rr) * 64;       // uniform -> s_load
        const float* x1 = x0 + 64;
        float a[2][2][4];
#pragma unroll
        for (int r = 0; r < 2; ++r)
#pragma unroll
            for (int cd = 0; cd < 2; ++cd)
#pragma unroll
                for (int c = 0; c < 4; ++c) a[r][cd][c] = 0.f;

#pragma unroll
        for (int d = 0; d < 64; ++d) {
            float xv0 = x0[d];
            float xv1 = x1[d];
            int c = d & 3;
            a[0][0][c] = __builtin_fmaf(xv0, e0r[d], a[0][0][c]);
            a[0][1][c] = __builtin_fmaf(xv0, e1r[d], a[0][1][c]);
            a[1][0][c] = __builtin_fmaf(xv1, e0r[d], a[1][0][c]);
            a[1][1][c] = __builtin_fmaf(xv1, e1r[d], a[1][1][c]);
        }

#pragma unroll
        for (int r = 0; r < 2; ++r) {
            float sx = sxs[rr + r];
            float dot0 = (a[r][0][0] + a[r][0][1]) + (a[r][0][2] + a[r][0][3]);
            float dot1 = (a[r][1][0] + a[r][1][1]) + (a[r][1][2] + a[r][1][3]);
            float dist0 = sx - 2.0f * dot0 + en0;
            float dist1 = sx - 2.0f * dot1 + en1;
            unsigned long long k0 = ((unsigned long long)__float_as_uint(dist0) << 32) | (unsigned)j0;
            unsigned long long k1 = ((unsigned long long)__float_as_uint(dist1) << 32) | (unsigned)j1;
            unsigned long long key = (k1 < k0) ? k1 : k0;
#pragma unroll
            for (int off = 1; off < 64; off <<= 1) {
                unsigned long long o = __shfl_xor(key, off, 64);
                if (o < key) key = o;
            }
            if (lane == 0) part[(row0 + rr + r) * 4 + w] = key;
        }
    }
}

// ---------------- VQ part 2: merge 4 per-wave keys per row; idx + loss accumulation ----------------
__global__ __launch_bounds__(256) void vq_merge(
    const unsigned long long* __restrict__ part,
    float* __restrict__ idxo, float* __restrict__ accum)
{
    __shared__ float wsum[4];
    const int t = threadIdx.x;
    const size_t row = (size_t)blockIdx.x * 256 + t;
    unsigned long long k = part[row * 4];
#pragma unroll
    for (int i = 1; i < 4; ++i) {
        unsigned long long o = part[row * 4 + i];
        if (o < k) k = o;
    }
    idxo[row] = (float)(unsigned)(k & 0xffffffffULL);
    float dist = __uint_as_float((unsigned)(k >> 32));
    for (int off = 32; off > 0; off >>= 1) dist += __shfl_down(dist, off, 64);
    if ((t & 63) == 0) wsum[t >> 6] = dist;
    __syncthreads();
    if (t == 0) atomicAdd(accum, wsum[0] + wsum[1] + wsum[2] + wsum[3]);
}

__global__ void vq_fin(const float* __restrict__ accum, float* __restrict__ out, float scale)
{
    out[0] = accum[0] * scale;
}

extern "C" void kernel_launch(void* const* d_in, const int* in_sizes, int n_in,
                              void* d_out, int out_size, void* d_ws, size_t ws_size,
                              hipStream_t stream)
{
    const float* x    = (const float*)d_in[0];
    const float* W_e0 = (const float*)d_in[1];
    const float* b_e0 = (const float*)d_in[2];
    const float* W_e1 = (const float*)d_in[3];
    const float* b_e1 = (const float*)d_in[4];
    const float* W_e2 = (const float*)d_in[5];
    const float* b_e2 = (const float*)d_in[6];
    const float* W_p  = (const float*)d_in[7];
    const float* b_p  = (const float*)d_in[8];
    const float* E    = (const float*)d_in[9];
    const float* W_a0 = (const float*)d_in[10];
    const float* b_a0 = (const float*)d_in[11];
    const float* W_a1 = (const float*)d_in[12];
    const float* b_a1 = (const float*)d_in[13];
    const float* W_c0 = (const float*)d_in[14];
    const float* b_c0 = (const float*)d_in[15];
    const float* W_c1 = (const float*)d_in[16];
    const float* b_c1 = (const float*)d_in[17];
    const float* W_c2 = (const float*)d_in[18];
    const float* b_c2 = (const float*)d_in[19];

    const size_t B = (size_t)in_sizes[0] / F_IN;   // 65536

    // ws: buf0 bf16 | buf1 bf16 (unused, layout kept) | wt bf16 | xq fp32 | part u64 | accum
    short* buf0 = (short*)d_ws;                       // B*128 bf16
    short* buf1 = buf0 + B * H_DIM;                   // B*128 bf16 (unused)
    short* wt   = buf1 + B * H_DIM;                   // 229376 bf16
    short* wt_e0 = wt;                                // [128][1024]
    short* wt_e1 = wt + 131072;                       // [128][128] each
    short* wt_e2 = wt_e1 + 16384;
    short* wt_a0 = wt_e2 + 16384;
    short* wt_a1 = wt_a0 + 16384;
    short* wt_c0 = wt_a1 + 16384;
    short* wt_c1 = wt_c0 + 16384;
    float* xq    = (float*)(wt + 229376);             // B*64 fp32
    unsigned long long* part = (unsigned long long*)(xq + B * D_VQE);  // B*4 u64 (8B-aligned)
    float* accum = (float*)(part + B * 4);

    // d_out is fp32: probs [B,128] | critic [B] | vq_loss [1] | idx [B]
    float* out   = (float*)d_out;
    float* probs = out;
    float* crit  = out + B * H_DIM;
    float* loss  = crit + B;
    float* idxo  = loss + 1;

    hipMemsetAsync(accum, 0, sizeof(float), stream);

    dim3 blk(256);
    const int nb128 = (int)(B / 128);

    conv_weights<<<dim3(896), blk, 0, stream>>>(W_e0, W_e1, W_e2, W_a0, W_a1, W_c0, W_c1, wt);

    // VQ path (verified fp32 chains)
    proj64<<<dim3((int)(B / 64)), blk, 0, stream>>>(x, W_p, b_p, xq);
    vq_part<<<dim3((int)(B / 64)), blk, 0, stream>>>(xq, E, part);
    vq_merge<<<dim3((int)(B / 256)), blk, 0, stream>>>(part, idxo, accum);
    vq_fin<<<1, 1, 0, stream>>>(accum, loss, 1.25f / ((float)B * (float)D_VQE));

    // tower: verified e0, then the fused tail (5 activation HBM round-trips removed)
    gemm_e0<<<dim3(nb128), blk, 0, stream>>>(x, wt_e0, b_e0, buf0);
    tower_tail<<<dim3(nb128), blk, 0, stream>>>(buf0,
        wt_e1, b_e1, wt_e2, b_e2, wt_a0, b_a0, wt_a1, b_a1,
        wt_c0, b_c0, wt_c1, b_c1, W_c2, b_c2, probs, crit);
}